// Round 1
// baseline (156.554 us; speedup 1.0000x reference)
//
#include <hip/hip_runtime.h>

typedef __attribute__((ext_vector_type(8))) short short8;
typedef __attribute__((ext_vector_type(4))) float floatx4;

#define MFMA16(a,b,c) __builtin_amdgcn_mfma_f32_16x16x32_bf16((a),(b),(c),0,0,0)

static __device__ __forceinline__ unsigned short f2bf(float f){
    unsigned int u = __float_as_uint(f);
    u = (u + 0x7FFFu + ((u >> 16) & 1u)) >> 16;
    return (unsigned short)u;
}

// async global->LDS, 16 B/lane; lds base must be wave-uniform, lane i lands at
// base + i*16 (m97/m104). Source address is per-lane (gather) -> lets us store
// XOR-swizzled layouts by permuting the SOURCE, not the destination.
static __device__ __forceinline__ void async16(const unsigned short* g, const unsigned short* l){
    __builtin_amdgcn_global_load_lds(
        (const __attribute__((address_space(1))) unsigned int*)g,
        (__attribute__((address_space(3))) unsigned int*)l, 16, 0, 0);
}

// ---------------------------------------------------------------------------
// Kernel 1: prep = transpose x + convert both weight matrices to bf16.
// ---------------------------------------------------------------------------
__global__ __launch_bounds__(256) void k_prep(const float* __restrict__ x,
                                              unsigned short* __restrict__ xT,
                                              const float* __restrict__ qkvw,
                                              unsigned short* __restrict__ wqkv,
                                              const float* __restrict__ outw,
                                              unsigned short* __restrict__ wout){
    __shared__ unsigned short tile[64][72];
    const int bid = blockIdx.x;
    const int tid = threadIdx.x;
    if (bid < 2048){
        const int c0 = (bid & 7) * 64;
        const int n0 = ((bid >> 3) & 3) * 64;
        const int b  = bid >> 5;
        const int chunk = tid & 7;
        const int r     = tid >> 3;
        const float*    src = x  + (size_t)b * 131072;
        unsigned short* dst = xT + (size_t)b * 131072;
#pragma unroll
        for (int it = 0; it < 2; ++it){
            int c = r + it * 32;
            const float* p = src + (size_t)(c0 + c) * 256 + n0 + chunk * 8;
            float4 f0 = *(const float4*)(p);
            float4 f1 = *(const float4*)(p + 4);
            short8 v;
            v[0]=(short)f2bf(f0.x); v[1]=(short)f2bf(f0.y); v[2]=(short)f2bf(f0.z); v[3]=(short)f2bf(f0.w);
            v[4]=(short)f2bf(f1.x); v[5]=(short)f2bf(f1.y); v[6]=(short)f2bf(f1.z); v[7]=(short)f2bf(f1.w);
            *(short8*)&tile[c][chunk * 8] = v;
        }
        __syncthreads();
#pragma unroll
        for (int it = 0; it < 2; ++it){
            int n = r + it * 32;
            short8 o;
#pragma unroll
            for (int e = 0; e < 8; ++e) o[e] = (short)tile[chunk * 8 + e][n];
            *(short8*)(dst + (size_t)(n0 + n) * 512 + c0 + chunk * 8) = o;
        }
    } else {
        int i = (bid - 2048) * 256 + tid;
        const float* s; unsigned short* d; int j;
        if (i < 196608){ s = qkvw; d = wqkv; j = i; }
        else { j = i - 196608; if (j >= 65536) return; s = outw; d = wout; }
        float4 f = *(const float4*)(s + (size_t)j * 4);
        uint2 v;
        v.x = (unsigned int)f2bf(f.x) | ((unsigned int)f2bf(f.y) << 16);
        v.y = (unsigned int)f2bf(f.z) | ((unsigned int)f2bf(f.w) << 16);
        *(uint2*)(d + (size_t)j * 4) = v;
    }
}

// ---------------------------------------------------------------------------
// Kernel 2: FUSED qkv-projection + attention, one block per (b, h).
// Phase A: [Q|K|V](256x192) = X_b(256x512) . W_slice^T, staged by DMA,
//          DOUBLE-BUFFERED (buf1 overlays the dead Q/K areas): stage tile t+1
//          while computing tile t, ONE barrier per K-step (T3-minimal).
// Phase B: S = Q K^T /8 + rel, single-pass softmax, O = P V, write ao.
// All LDS tiles XOR-chunk-swizzled: phys_chunk = chunk ^ (row & 7)
// (low 3 bits) -> conflict-free b128 reads with DMA-contiguous rows.
// ---------------------------------------------------------------------------
__global__ __launch_bounds__(512, 2) void k_fused(const unsigned short* __restrict__ xT,
                                                  const unsigned short* __restrict__ wbf,
                                                  const float* __restrict__ qkvb,
                                                  const float* __restrict__ rel,
                                                  unsigned short* __restrict__ ao){
    __shared__ unsigned short SH[79748];          // 159,496 B
    const int XS = 0;          // X stage buf0  256x64
    const int WS = 16384;      // W stage buf0  192x64
    const int QS = 28672;      // Q 256x64   (doubles as X stage buf1 in phase A)
    const int KS = 45056;      // K 256x64   (doubles as W stage buf1 in phase A)
    const int VS = 61440;      // V  64x256 (head-major)
    float* Relsh = (float*)&SH[77824];            // 961 fp32

    const int bid  = blockIdx.x;
    const int xcd  = bid & 7;
    const int slot = bid >> 3;                    // 0..63
    const int b = xcd * 8 + (slot & 7);           // all 8 heads of a b-octet on one XCD
    const int h = slot >> 3;
    const int tid  = threadIdx.x;
    const int wave = tid >> 6;
    const int lane = tid & 63;
    const int lrow = lane & 15;
    const int lgrp = lane >> 4;
    const int mq = wave >> 1;                     // M-quarter (64 tokens)
    const int nh = wave & 1;                      // N-half (96 cols)

    for (int i = tid; i < 961; i += 512) Relsh[i] = rel[h * 961 + i];

    // ---- phase A: QKV mini-GEMM -------------------------------------------
    floatx4 acc[4][6];
#pragma unroll
    for (int i = 0; i < 4; ++i)
#pragma unroll
        for (int j = 0; j < 6; ++j){ floatx4 z = {0.f,0.f,0.f,0.f}; acc[i][j] = z; }

    const unsigned short* xb = xT + (size_t)(b * 256) * 512;
    // DMA source pointers (kk added in loop); swizzle by permuting source chunk
    const unsigned short* xsrc[4]; int xdo[4];
#pragma unroll
    for (int c = 0; c < 4; ++c){
        int s   = (c * 8 + wave) * 64 + lane;     // 0..2047
        int row = s >> 3, pch = s & 7;
        int sch = pch ^ (row & 7);
        xsrc[c] = xb + (size_t)row * 512 + sch * 8;
        xdo[c]  = (c * 8 + wave) * 512;           // short offset inside buffer
    }
    const unsigned short* wsrc[3]; int wdo[3];
#pragma unroll
    for (int c = 0; c < 3; ++c){
        int s   = (c * 8 + wave) * 64 + lane;     // 0..1535
        int row = s >> 3, pch = s & 7;
        int sch = pch ^ (row & 7);
        int grow = (row >> 6) * 512 + h * 64 + (row & 63);   // q/k/v row slices
        wsrc[c] = wbf + (size_t)grow * 512 + sch * 8;
        wdo[c]  = (c * 8 + wave) * 512;
    }

    auto stageA = [&](int XBs, int WBs, int kk){
#pragma unroll
        for (int c = 0; c < 4; ++c) async16(xsrc[c] + kk, &SH[XBs + xdo[c]]);
#pragma unroll
        for (int c = 0; c < 3; ++c) async16(wsrc[c] + kk, &SH[WBs + wdo[c]]);
    };
    auto compA = [&](int XBs, int WBs){
#pragma unroll
        for (int ks = 0; ks < 2; ++ks){
            short8 af[4], bq[6];
#pragma unroll
            for (int mt = 0; mt < 4; ++mt){
                int row = mq * 64 + mt * 16 + lrow;
                int pch = (ks * 4 + lgrp) ^ (row & 7);
                af[mt] = *(const short8*)&SH[XBs + row * 64 + pch * 8];
            }
#pragma unroll
            for (int nt = 0; nt < 6; ++nt){
                int row = nh * 96 + nt * 16 + lrow;
                int pch = (ks * 4 + lgrp) ^ (row & 7);
                bq[nt] = *(const short8*)&SH[WBs + row * 64 + pch * 8];
            }
#pragma unroll
            for (int mt = 0; mt < 4; ++mt)
#pragma unroll
                for (int nt = 0; nt < 6; ++nt)
                    acc[mt][nt] = MFMA16(af[mt], bq[nt], acc[mt][nt]);
        }
    };

    // prologue: tile 0 -> buf0; steady state: stage t+1 while computing t.
    stageA(XS, WS, 0);
    __syncthreads();                              // also covers Relsh writes
#pragma unroll
    for (int t2 = 0; t2 < 4; ++t2){
        stageA(QS, KS, t2 * 128 + 64);            // tiles 1,3,5,7 -> buf1
        compA(XS, WS);                            // tiles 0,2,4,6
        __syncthreads();
        if (t2 < 3) stageA(XS, WS, t2 * 128 + 128); // tiles 2,4,6 -> buf0
        compA(QS, KS);                            // tiles 1,3,5,7
        __syncthreads();
    }

    // epilogue A: +bias, bf16, scatter into Q/K/V LDS
#pragma unroll
    for (int mt = 0; mt < 4; ++mt){
#pragma unroll
        for (int nt = 0; nt < 6; ++nt){
            int col = nh * 96 + nt * 16 + lrow;
            int seg = col >> 6, off = col & 63;
            float bv = qkvb[seg * 512 + h * 64 + off];
#pragma unroll
            for (int r = 0; r < 4; ++r){
                int token = mq * 64 + mt * 16 + lgrp * 4 + r;
                unsigned short v = f2bf(acc[mt][nt][r] + bv);
                if (seg == 2){
                    int lch = token >> 3;
                    int pch = (lch & 24) | ((lch & 7) ^ (off & 7));
                    SH[VS + off * 256 + pch * 8 + (token & 7)] = v;
                } else {
                    int base = seg ? KS : QS;
                    int pch  = (off >> 3) ^ (token & 7);
                    SH[base + token * 64 + pch * 8 + (off & 7)] = v;
                }
            }
        }
    }
    __syncthreads();

    // ---- phase B: attention -----------------------------------------------
    short8 aq[2][2];
#pragma unroll
    for (int pp = 0; pp < 2; ++pp)
#pragma unroll
        for (int kc = 0; kc < 2; ++kc){
            int row = wave * 32 + pp * 16 + lrow;
            int pch = (kc * 4 + lgrp) ^ (row & 7);
            aq[pp][kc] = *(const short8*)&SH[QS + row * 64 + pch * 8];
        }

    floatx4 s2[2][16];
#pragma unroll
    for (int pp = 0; pp < 2; ++pp)
#pragma unroll
        for (int ct = 0; ct < 16; ++ct){
            int row = ct * 16 + lrow;
            int pch0 = lgrp ^ (row & 7);
            short8 b0 = *(const short8*)&SH[KS + row * 64 + pch0 * 8];
            short8 b1 = *(const short8*)&SH[KS + row * 64 + (pch0 ^ 4) * 8];
            floatx4 z = {0.f,0.f,0.f,0.f};
            z = MFMA16(aq[pp][0], b0, z);
            z = MFMA16(aq[pp][1], b1, z);
            s2[pp][ct] = z;
        }

    float inv[2][4];
#pragma unroll
    for (int pp = 0; pp < 2; ++pp)
#pragma unroll
        for (int r = 0; r < 4; ++r){
            int n   = wave * 32 + pp * 16 + lgrp * 4 + r;
            int nh_ = n >> 4, nw = n & 15;
            float sum = 0.f;
#pragma unroll
            for (int ct = 0; ct < 16; ++ct){
                float e = __expf(s2[pp][ct][r] * 0.125f +
                                 Relsh[(nh_ - ct + 15) * 31 + (nw - lrow + 15)]);
                s2[pp][ct][r] = e;
                sum += e;
            }
#pragma unroll
            for (int off = 1; off < 16; off <<= 1)
                sum += __shfl_xor(sum, off, 64);
            inv[pp][r] = 1.f / sum;
        }

    __syncthreads();                      // Q,K reads done -> safe to overlay P

    const int PB = QS + wave * 4096;      // per-wave P (16x256), overlays Q/K
    unsigned short* aob = ao + (size_t)(b * 256) * 512 + h * 64;
#pragma unroll
    for (int pp = 0; pp < 2; ++pp){
#pragma unroll
        for (int ct = 0; ct < 16; ++ct)
#pragma unroll
            for (int r = 0; r < 4; ++r){
                int row = lgrp * 4 + r;
                int lch = ct * 2 + (lrow >> 3);
                int pch = (lch & 24) | ((lch & 7) ^ (row & 7));
                SH[PB + row * 256 + pch * 8 + (lrow & 7)] = f2bf(s2[pp][ct][r]);
            }
        short8 pa[8];
#pragma unroll
        for (int ms = 0; ms < 8; ++ms){
            int lch = ms * 4 + lgrp;
            int pch = (lch & 24) | ((lch & 7) ^ (lrow & 7));
            pa[ms] = *(const short8*)&SH[PB + lrow * 256 + pch * 8];
        }
#pragma unroll
        for (int dt = 0; dt < 4; ++dt){
            floatx4 accO = {0.f,0.f,0.f,0.f};
#pragma unroll
            for (int ms = 0; ms < 8; ++ms){
                int row = dt * 16 + lrow;
                int lch = ms * 4 + lgrp;
                int pch = (lch & 24) | ((lch & 7) ^ (row & 7));
                short8 vb = *(const short8*)&SH[VS + row * 256 + pch * 8];
                accO = MFMA16(pa[ms], vb, accO);
            }
#pragma unroll
            for (int r = 0; r < 4; ++r){
                int n = wave * 32 + pp * 16 + lgrp * 4 + r;
                aob[(size_t)n * 512 + dt * 16 + lrow] = f2bf(accO[r] * inv[pp][r]);
            }
        }
    }
}

// ---------------------------------------------------------------------------
// Kernel 3: out projection, DOUBLE-BUFFERED 2-stage K-loop + XCD swizzle
// (512 blocks), fp32 out[b,o,n].
// ---------------------------------------------------------------------------
__global__ __launch_bounds__(256, 2) void k_out(const unsigned short* __restrict__ ao,
                                                const unsigned short* __restrict__ wbf,
                                                const float* __restrict__ bias,
                                                float* __restrict__ out){
    __shared__ unsigned short Ash[2][2][128][32];   // [dbuf][kslice][row][col]
    __shared__ unsigned short Bsh[2][2][128][32];
    const int bid  = blockIdx.x;
    const int xcd  = bid & 7;
    const int slot = bid >> 3;
    const int t0 = (xcd * 16 + (slot & 15)) * 128;
    const int o0 = (slot >> 4) * 128;
    const int tid  = threadIdx.x;
    const int wave = tid >> 6;
    const int lane = tid & 63;
    const int lrow = lane & 15;
    const int lk8  = (lane >> 4) * 8;
    const int wm   = (wave >> 1) * 64;
    const int wn   = (wave & 1) * 64;
    const int ld_row = wave * 32 + (lane >> 2);
    const int ld_col = (lane & 3) * 8;

    floatx4 acc[4][4];
#pragma unroll
    for (int i = 0; i < 4; ++i)
#pragma unroll
        for (int j = 0; j < 4; ++j){ floatx4 z = {0.f,0.f,0.f,0.f}; acc[i][j] = z; }

    const unsigned short* gA = wbf + (size_t)(o0 + ld_row) * 512 + ld_col;
    const unsigned short* gB = ao  + (size_t)(t0 + ld_row) * 512 + ld_col;

    auto stage = [&](int d, int kk){
        async16(gA + kk,                 &Ash[d][0][wave * 32][0]);
        async16(gA + kk + 16 * 512,      &Ash[d][0][wave * 32 + 16][0]);
        async16(gA + kk + 32,            &Ash[d][1][wave * 32][0]);
        async16(gA + kk + 32 + 16 * 512, &Ash[d][1][wave * 32 + 16][0]);
        async16(gB + kk,                 &Bsh[d][0][wave * 32][0]);
        async16(gB + kk + 16 * 512,      &Bsh[d][0][wave * 32 + 16][0]);
        async16(gB + kk + 32,            &Bsh[d][1][wave * 32][0]);
        async16(gB + kk + 32 + 16 * 512, &Bsh[d][1][wave * 32 + 16][0]);
    };
    auto comp = [&](int d){
#pragma unroll
        for (int s = 0; s < 2; ++s){
            short8 af[4], bq[4];
#pragma unroll
            for (int mt = 0; mt < 4; ++mt) af[mt] = *(const short8*)&Ash[d][s][wm + mt*16 + lrow][lk8];
#pragma unroll
            for (int nt = 0; nt < 4; ++nt) bq[nt] = *(const short8*)&Bsh[d][s][wn + nt*16 + lrow][lk8];
#pragma unroll
            for (int mt = 0; mt < 4; ++mt)
#pragma unroll
                for (int nt = 0; nt < 4; ++nt)
                    acc[mt][nt] = MFMA16(af[mt], bq[nt], acc[mt][nt]);
        }
    };

    stage(0, 0);
    __syncthreads();
#pragma unroll
    for (int t2 = 0; t2 < 4; ++t2){
        stage(1, t2 * 128 + 64);          // tiles 1,3,5,7
        comp(0);                          // tiles 0,2,4,6
        __syncthreads();
        if (t2 < 3) stage(0, t2 * 128 + 128); // tiles 2,4,6
        comp(1);                          // tiles 1,3,5,7
        __syncthreads();
    }
#pragma unroll
    for (int mt = 0; mt < 4; ++mt){
        int orow0 = o0 + wm + mt*16 + (lane >> 4) * 4;
#pragma unroll
        for (int nt = 0; nt < 4; ++nt){
            int tcol = t0 + wn + nt*16 + lrow;
            int bb = tcol >> 8, nn = tcol & 255;
#pragma unroll
            for (int r = 0; r < 4; ++r){
                float bv = bias[orow0 + r];
                out[(size_t)(bb * 512 + orow0 + r) * 256 + nn] = acc[mt][nt][r] + bv;
            }
        }
    }
}

// ---------------------------------------------------------------------------
extern "C" void kernel_launch(void* const* d_in, const int* in_sizes, int n_in,
                              void* d_out, int out_size, void* d_ws, size_t ws_size,
                              hipStream_t stream){
    const float* x    = (const float*)d_in[0];
    const float* qkvw = (const float*)d_in[1];
    const float* qkvb = (const float*)d_in[2];
    const float* outw = (const float*)d_in[3];
    const float* outb = (const float*)d_in[4];
    const float* rel  = (const float*)d_in[5];
    float* out = (float*)d_out;

    // workspace: XT (16 MiB) | AO (16 MiB) | weights (2.5 MiB)
    const size_t XT_OFF = 0;
    const size_t AO_OFF = 16777216;
    const size_t W_OFF  = 33554432;
    const size_t NEED   = W_OFF + 4194304;
    if (ws_size < NEED) return;

    char* ws = (char*)d_ws;
    unsigned short* xT = (unsigned short*)(ws + XT_OFF);
    unsigned short* ao = (unsigned short*)(ws + AO_OFF);
    unsigned short* wqkv_bf = (unsigned short*)(ws + W_OFF);
    unsigned short* wout_bf = (unsigned short*)(ws + W_OFF + 2097152);

    hipLaunchKernelGGL(k_prep,  dim3(3072), dim3(256), 0, stream,
                       x, xT, qkvw, wqkv_bf, outw, wout_bf);
    hipLaunchKernelGGL(k_fused, dim3(512),  dim3(512), 0, stream,
                       xT, wqkv_bf, qkvb, rel, ao);
    hipLaunchKernelGGL(k_out,   dim3(512),  dim3(256), 0, stream,
                       ao, wout_bf, outb, out);
}

// Round 2
// 151.227 us; speedup vs baseline: 1.0352x; 1.0352x over previous
//
#include <hip/hip_runtime.h>

typedef __attribute__((ext_vector_type(8))) short short8;
typedef __attribute__((ext_vector_type(4))) float floatx4;
typedef __attribute__((ext_vector_type(4))) int   intx4;

#define MFMA16(a,b,c) __builtin_amdgcn_mfma_f32_16x16x32_bf16((a),(b),(c),0,0,0)

static __device__ __forceinline__ unsigned short f2bf(float f){
    unsigned int u = __float_as_uint(f);
    u = (u + 0x7FFFu + ((u >> 16) & 1u)) >> 16;
    return (unsigned short)u;
}

// pack two f32 -> 2xbf16 in one u32 (low = first arg)
static __device__ __forceinline__ unsigned int pkbf(float lo, float hi){
    unsigned int r;
    asm("v_cvt_pk_bf16_f32 %0, %1, %2" : "=v"(r) : "v"(lo), "v"(hi));
    return r;
}

// async global->LDS, 16 B/lane; lds base must be wave-uniform, lane i lands at
// base + i*16 (m97/m104). Source address is per-lane (gather) -> lets us store
// XOR-swizzled layouts by permuting the SOURCE, not the destination.
static __device__ __forceinline__ void async16(const unsigned short* g, const unsigned short* l){
    __builtin_amdgcn_global_load_lds(
        (const __attribute__((address_space(1))) unsigned int*)g,
        (__attribute__((address_space(3))) unsigned int*)l, 16, 0, 0);
}

// ---------------------------------------------------------------------------
// Kernel 1: prep = transpose x + convert both weight matrices to bf16.
// tile stride 78 shorts (39 dwords): write banks 7c+4chunk -> <=2-way; gather
// banks 24*chunk+... -> 2-way. (72 was 8-way on both sides.)
// ---------------------------------------------------------------------------
__global__ __launch_bounds__(256) void k_prep(const float* __restrict__ x,
                                              unsigned short* __restrict__ xT,
                                              const float* __restrict__ qkvw,
                                              unsigned short* __restrict__ wqkv,
                                              const float* __restrict__ outw,
                                              unsigned short* __restrict__ wout){
    __shared__ unsigned short tile[64][78];
    const int bid = blockIdx.x;
    const int tid = threadIdx.x;
    if (bid < 2048){
        const int c0 = (bid & 7) * 64;
        const int n0 = ((bid >> 3) & 3) * 64;
        const int b  = bid >> 5;
        const int chunk = tid & 7;
        const int r     = tid >> 3;
        const float*    src = x  + (size_t)b * 131072;
        unsigned short* dst = xT + (size_t)b * 131072;
#pragma unroll
        for (int it = 0; it < 2; ++it){
            int c = r + it * 32;
            const float* p = src + (size_t)(c0 + c) * 256 + n0 + chunk * 8;
            float4 f0 = *(const float4*)(p);
            float4 f1 = *(const float4*)(p + 4);
            short8 v;
            v[0]=(short)f2bf(f0.x); v[1]=(short)f2bf(f0.y); v[2]=(short)f2bf(f0.z); v[3]=(short)f2bf(f0.w);
            v[4]=(short)f2bf(f1.x); v[5]=(short)f2bf(f1.y); v[6]=(short)f2bf(f1.z); v[7]=(short)f2bf(f1.w);
            *(short8*)&tile[c][chunk * 8] = v;
        }
        __syncthreads();
#pragma unroll
        for (int it = 0; it < 2; ++it){
            int n = r + it * 32;
            short8 o;
#pragma unroll
            for (int e = 0; e < 8; ++e) o[e] = (short)tile[chunk * 8 + e][n];
            *(short8*)(dst + (size_t)(n0 + n) * 512 + c0 + chunk * 8) = o;
        }
    } else {
        int i = (bid - 2048) * 256 + tid;
        const float* s; unsigned short* d; int j;
        if (i < 196608){ s = qkvw; d = wqkv; j = i; }
        else { j = i - 196608; if (j >= 65536) return; s = outw; d = wout; }
        float4 f = *(const float4*)(s + (size_t)j * 4);
        uint2 v;
        v.x = (unsigned int)f2bf(f.x) | ((unsigned int)f2bf(f.y) << 16);
        v.y = (unsigned int)f2bf(f.z) | ((unsigned int)f2bf(f.w) << 16);
        *(uint2*)(d + (size_t)j * 4) = v;
    }
}

// ---------------------------------------------------------------------------
// Kernel 2: FUSED qkv-projection + attention, one block per (b, h).
// Phase A: [Q|K|V](256x192) = X_b(256x512) . W_slice^T, DMA double-buffered.
// Phase B: SWAPPED-OPERAND attention: S^T = MFMA(K,Q). K rows stored at
// permuted slots rho^-1(t) (rotate bits {4,3,2}) so that each lane's S^T
// registers are exactly the P^T B-fragment for PV -> NO LDS round-trip for P,
// no cross-lane ops, no extra barrier. Softmax in exp2 domain (scales folded
// into Q and Relsh). O written as uint2 (bf16x4).
// ---------------------------------------------------------------------------
__global__ __launch_bounds__(512, 2) void k_fused(const unsigned short* __restrict__ xT,
                                                  const unsigned short* __restrict__ wbf,
                                                  const float* __restrict__ qkvb,
                                                  const float* __restrict__ rel,
                                                  unsigned short* __restrict__ ao){
    __shared__ unsigned short SH[79748];          // 159,496 B
    const int XS = 0;          // X stage buf0  256x64
    const int WS = 16384;      // W stage buf0  192x64
    const int QS = 28672;      // Q 256x64   (doubles as X stage buf1 in phase A)
    const int KS = 45056;      // K 256x64   (doubles as W stage buf1 in phase A)
    const int VS = 61440;      // V  64x256 (head-major)
    float* Relsh = (float*)&SH[77824];            // 961 fp32 (pre-scaled by log2e)

    const int bid  = blockIdx.x;
    const int xcd  = bid & 7;
    const int slot = bid >> 3;                    // 0..63
    const int b = xcd * 8 + (slot & 7);           // all 8 heads of a b-octet on one XCD
    const int h = slot >> 3;
    const int tid  = threadIdx.x;
    const int wave = tid >> 6;
    const int lane = tid & 63;
    const int lrow = lane & 15;
    const int lgrp = lane >> 4;
    const int mq = wave >> 1;                     // M-quarter (64 tokens)
    const int nh = wave & 1;                      // N-half (96 cols)

    for (int i = tid; i < 961; i += 512) Relsh[i] = rel[h * 961 + i] * 1.44269504f;

    // ---- phase A: QKV mini-GEMM -------------------------------------------
    floatx4 acc[4][6];
#pragma unroll
    for (int i = 0; i < 4; ++i)
#pragma unroll
        for (int j = 0; j < 6; ++j){ floatx4 z = {0.f,0.f,0.f,0.f}; acc[i][j] = z; }

    const unsigned short* xb = xT + (size_t)(b * 256) * 512;
    const unsigned short* xsrc[4]; int xdo[4];
#pragma unroll
    for (int c = 0; c < 4; ++c){
        int s   = (c * 8 + wave) * 64 + lane;     // 0..2047
        int row = s >> 3, pch = s & 7;
        int sch = pch ^ (row & 7);
        xsrc[c] = xb + (size_t)row * 512 + sch * 8;
        xdo[c]  = (c * 8 + wave) * 512;
    }
    const unsigned short* wsrc[3]; int wdo[3];
#pragma unroll
    for (int c = 0; c < 3; ++c){
        int s   = (c * 8 + wave) * 64 + lane;     // 0..1535
        int row = s >> 3, pch = s & 7;
        int sch = pch ^ (row & 7);
        int grow = (row >> 6) * 512 + h * 64 + (row & 63);   // q/k/v row slices
        wsrc[c] = wbf + (size_t)grow * 512 + sch * 8;
        wdo[c]  = (c * 8 + wave) * 512;
    }

    auto stageA = [&](int XBs, int WBs, int kk){
#pragma unroll
        for (int c = 0; c < 4; ++c) async16(xsrc[c] + kk, &SH[XBs + xdo[c]]);
#pragma unroll
        for (int c = 0; c < 3; ++c) async16(wsrc[c] + kk, &SH[WBs + wdo[c]]);
    };
    auto compA = [&](int XBs, int WBs){
#pragma unroll
        for (int ks = 0; ks < 2; ++ks){
            short8 af[4], bq[6];
#pragma unroll
            for (int mt = 0; mt < 4; ++mt){
                int row = mq * 64 + mt * 16 + lrow;
                int pch = (ks * 4 + lgrp) ^ (row & 7);
                af[mt] = *(const short8*)&SH[XBs + row * 64 + pch * 8];
            }
#pragma unroll
            for (int nt = 0; nt < 6; ++nt){
                int row = nh * 96 + nt * 16 + lrow;
                int pch = (ks * 4 + lgrp) ^ (row & 7);
                bq[nt] = *(const short8*)&SH[WBs + row * 64 + pch * 8];
            }
#pragma unroll
            for (int mt = 0; mt < 4; ++mt)
#pragma unroll
                for (int nt = 0; nt < 6; ++nt)
                    acc[mt][nt] = MFMA16(af[mt], bq[nt], acc[mt][nt]);
        }
    };

    stageA(XS, WS, 0);
    __syncthreads();                              // also covers Relsh writes
#pragma unroll
    for (int t2 = 0; t2 < 4; ++t2){
        stageA(QS, KS, t2 * 128 + 64);            // tiles 1,3,5,7 -> buf1
        compA(XS, WS);                            // tiles 0,2,4,6
        __syncthreads();
        if (t2 < 3) stageA(XS, WS, t2 * 128 + 128); // tiles 2,4,6 -> buf0
        compA(QS, KS);                            // tiles 1,3,5,7
        __syncthreads();
    }

    // epilogue A: +bias, bf16, scatter into Q/K/V LDS.
    // Q pre-scaled by 0.125*log2e; K rows go to permuted slot rho^-1(token).
#pragma unroll
    for (int mt = 0; mt < 4; ++mt){
#pragma unroll
        for (int nt = 0; nt < 6; ++nt){
            int col = nh * 96 + nt * 16 + lrow;
            int seg = col >> 6, off = col & 63;
            float bv = qkvb[seg * 512 + h * 64 + off];
            int token0 = mq * 64 + mt * 16 + lgrp * 4;
            if (seg == 2){
                int lch = token0 >> 3;
                int pch = (lch & 24) | ((lch & 7) ^ (off & 7));
                uint2 vv;
                vv.x = pkbf(acc[mt][nt][0] + bv, acc[mt][nt][1] + bv);
                vv.y = pkbf(acc[mt][nt][2] + bv, acc[mt][nt][3] + bv);
                *(uint2*)&SH[VS + off * 256 + pch * 8 + (lgrp & 1) * 4] = vv;
            } else if (seg == 1){
#pragma unroll
                for (int r = 0; r < 4; ++r){
                    int token = token0 + r;
                    int kslot = (token & ~0x1C) | ((token & 4) << 2) | ((token & 0x18) >> 1);
                    int pch   = (off >> 3) ^ (kslot & 7);
                    SH[KS + kslot * 64 + pch * 8 + (off & 7)] = f2bf(acc[mt][nt][r] + bv);
                }
            } else {
#pragma unroll
                for (int r = 0; r < 4; ++r){
                    int token = token0 + r;
                    int pch   = (off >> 3) ^ (token & 7);
                    SH[QS + token * 64 + pch * 8 + (off & 7)] =
                        f2bf((acc[mt][nt][r] + bv) * 0.18033688f);
                }
            }
        }
    }
    __syncthreads();

    // ---- phase B: attention (LDS read-only, no barriers) -------------------
    short8 aq[2][2];
#pragma unroll
    for (int pp = 0; pp < 2; ++pp)
#pragma unroll
        for (int kc = 0; kc < 2; ++kc){
            int row = wave * 32 + pp * 16 + lrow;
            int pch = (kc * 4 + lgrp) ^ (row & 7);
            aq[pp][kc] = *(const short8*)&SH[QS + row * 64 + pch * 8];
        }

    unsigned short* aob = ao + (size_t)(b * 256) * 512 + h * 64;
    const int khB = lgrp >> 1;
    const int kwB = (lgrp & 1) * 8;

#pragma unroll
    for (int pp = 0; pp < 2; ++pp){
        // S^T = K . Q^T : lane holds S[key = 32*(ct>>1)+8*lgrp+4*(ct&1)+r][tok=lrow]
        floatx4 st[16];
        __builtin_amdgcn_s_setprio(1);
#pragma unroll
        for (int ct = 0; ct < 16; ++ct){
            int row  = ct * 16 + lrow;
            int pch0 = lgrp ^ (row & 7);
            short8 k0 = *(const short8*)&SH[KS + row * 64 + pch0 * 8];
            short8 k1 = *(const short8*)&SH[KS + row * 64 + (pch0 ^ 4) * 8];
            floatx4 z = {0.f,0.f,0.f,0.f};
            z = MFMA16(k0, aq[pp][0], z);
            z = MFMA16(k1, aq[pp][1], z);
            st[ct] = z;
        }
        __builtin_amdgcn_s_setprio(0);

        // softmax in exp2 domain
        float sum = 0.f;
        const int rbase = (wave * 2 + pp + 15) * 31 + lrow + 15 - kwB;
#pragma unroll
        for (int ct = 0; ct < 16; ++ct){
            int rb = rbase - (2 * (ct >> 1) + khB) * 31 - 4 * (ct & 1);
#pragma unroll
            for (int r = 0; r < 4; ++r){
                float e = __builtin_amdgcn_exp2f(st[ct][r] + Relsh[rb - r]);
                st[ct][r] = e;
                sum += e;
            }
        }
        sum += __shfl_xor(sum, 16, 64);
        sum += __shfl_xor(sum, 32, 64);
        float inv = 1.f / sum;

        // pack P^T fragments (lane-local thanks to K slot permutation)
        intx4 pf[8];
#pragma unroll
        for (int ms = 0; ms < 8; ++ms){
            intx4 t;
            t.x = (int)pkbf(st[2*ms  ][0], st[2*ms  ][1]);
            t.y = (int)pkbf(st[2*ms  ][2], st[2*ms  ][3]);
            t.z = (int)pkbf(st[2*ms+1][0], st[2*ms+1][1]);
            t.w = (int)pkbf(st[2*ms+1][2], st[2*ms+1][3]);
            pf[ms] = t;
        }

        // O^T = V^T . P^T ; lane ends with O[d = dt*16+lgrp*4+r][tok = lrow]
        const int n = wave * 32 + pp * 16 + lrow;
        __builtin_amdgcn_s_setprio(1);
#pragma unroll
        for (int dt = 0; dt < 4; ++dt){
            floatx4 accO = {0.f,0.f,0.f,0.f};
#pragma unroll
            for (int ms = 0; ms < 8; ++ms){
                int row = dt * 16 + lrow;
                int lch = ms * 4 + lgrp;
                int pch = (lch & 24) | ((lch & 7) ^ (row & 7));
                short8 vb = *(const short8*)&SH[VS + row * 256 + pch * 8];
                accO = MFMA16(vb, __builtin_bit_cast(short8, pf[ms]), accO);
            }
            uint2 ov;
            ov.x = pkbf(accO[0] * inv, accO[1] * inv);
            ov.y = pkbf(accO[2] * inv, accO[3] * inv);
            *(uint2*)(aob + (size_t)n * 512 + dt * 16 + lgrp * 4) = ov;
        }
        __builtin_amdgcn_s_setprio(0);
    }
}

// ---------------------------------------------------------------------------
// Kernel 3: out projection, double-buffered, XCD swizzle, fp32 out[b,o,n].
// LDS chunk-XOR swizzle: phys16B-chunk = chunk ^ ((row>>1)&3), applied on DMA
// SOURCE and read side (rule 21) -> frag reads drop 8-way -> 2-way conflicts.
// ---------------------------------------------------------------------------
__global__ __launch_bounds__(256, 2) void k_out(const unsigned short* __restrict__ ao,
                                                const unsigned short* __restrict__ wbf,
                                                const float* __restrict__ bias,
                                                float* __restrict__ out){
    __shared__ unsigned short Ash[2][2][128][32];   // [dbuf][kslice][row][col]
    __shared__ unsigned short Bsh[2][2][128][32];
    const int bid  = blockIdx.x;
    const int xcd  = bid & 7;
    const int slot = bid >> 3;
    const int t0 = (xcd * 16 + (slot & 15)) * 128;
    const int o0 = (slot >> 4) * 128;
    const int tid  = threadIdx.x;
    const int wave = tid >> 6;
    const int lane = tid & 63;
    const int lrow = lane & 15;
    const int wm   = (wave >> 1) * 64;
    const int wn   = (wave & 1) * 64;
    const int ld_row = wave * 32 + (lane >> 2);
    // source col permuted by the dest row's swizzle: phys chunk (lane&3) holds
    // logical chunk (lane&3)^((ld_row>>1)&3); (row>>1)&3 == (lane>>3)&3 here.
    const int ld_col = (((lane & 3) ^ ((lane >> 3) & 3))) * 8;
    // read-side phys chunk for frag rows (row = 16*k + lrow): ((row>>1)&3) == ((lrow>>1)&3)
    const int pcho = (((lane >> 4) ^ ((lrow >> 1) & 3))) * 8;

    floatx4 acc[4][4];
#pragma unroll
    for (int i = 0; i < 4; ++i)
#pragma unroll
        for (int j = 0; j < 4; ++j){ floatx4 z = {0.f,0.f,0.f,0.f}; acc[i][j] = z; }

    const unsigned short* gA = wbf + (size_t)(o0 + ld_row) * 512 + ld_col;
    const unsigned short* gB = ao  + (size_t)(t0 + ld_row) * 512 + ld_col;

    auto stage = [&](int d, int kk){
        async16(gA + kk,                 &Ash[d][0][wave * 32][0]);
        async16(gA + kk + 16 * 512,      &Ash[d][0][wave * 32 + 16][0]);
        async16(gA + kk + 32,            &Ash[d][1][wave * 32][0]);
        async16(gA + kk + 32 + 16 * 512, &Ash[d][1][wave * 32 + 16][0]);
        async16(gB + kk,                 &Bsh[d][0][wave * 32][0]);
        async16(gB + kk + 16 * 512,      &Bsh[d][0][wave * 32 + 16][0]);
        async16(gB + kk + 32,            &Bsh[d][1][wave * 32][0]);
        async16(gB + kk + 32 + 16 * 512, &Bsh[d][1][wave * 32 + 16][0]);
    };
    auto comp = [&](int d){
#pragma unroll
        for (int s = 0; s < 2; ++s){
            short8 af[4], bq[4];
#pragma unroll
            for (int mt = 0; mt < 4; ++mt) af[mt] = *(const short8*)&Ash[d][s][wm + mt*16 + lrow][pcho];
#pragma unroll
            for (int nt = 0; nt < 4; ++nt) bq[nt] = *(const short8*)&Bsh[d][s][wn + nt*16 + lrow][pcho];
#pragma unroll
            for (int mt = 0; mt < 4; ++mt)
#pragma unroll
                for (int nt = 0; nt < 4; ++nt)
                    acc[mt][nt] = MFMA16(af[mt], bq[nt], acc[mt][nt]);
        }
    };

    stage(0, 0);
    __syncthreads();
#pragma unroll
    for (int t2 = 0; t2 < 4; ++t2){
        stage(1, t2 * 128 + 64);          // tiles 1,3,5,7
        comp(0);                          // tiles 0,2,4,6
        __syncthreads();
        if (t2 < 3) stage(0, t2 * 128 + 128); // tiles 2,4,6
        comp(1);                          // tiles 1,3,5,7
        __syncthreads();
    }
#pragma unroll
    for (int mt = 0; mt < 4; ++mt){
        int orow0 = o0 + wm + mt*16 + (lane >> 4) * 4;
#pragma unroll
        for (int nt = 0; nt < 4; ++nt){
            int tcol = t0 + wn + nt*16 + lrow;
            int bb = tcol >> 8, nn = tcol & 255;
#pragma unroll
            for (int r = 0; r < 4; ++r){
                float bv = bias[orow0 + r];
                out[(size_t)(bb * 512 + orow0 + r) * 256 + nn] = acc[mt][nt][r] + bv;
            }
        }
    }
}

// ---------------------------------------------------------------------------
extern "C" void kernel_launch(void* const* d_in, const int* in_sizes, int n_in,
                              void* d_out, int out_size, void* d_ws, size_t ws_size,
                              hipStream_t stream){
    const float* x    = (const float*)d_in[0];
    const float* qkvw = (const float*)d_in[1];
    const float* qkvb = (const float*)d_in[2];
    const float* outw = (const float*)d_in[3];
    const float* outb = (const float*)d_in[4];
    const float* rel  = (const float*)d_in[5];
    float* out = (float*)d_out;

    // workspace: XT (16 MiB) | AO (16 MiB) | weights (2.5 MiB)
    const size_t XT_OFF = 0;
    const size_t AO_OFF = 16777216;
    const size_t W_OFF  = 33554432;
    const size_t NEED   = W_OFF + 4194304;
    if (ws_size < NEED) return;

    char* ws = (char*)d_ws;
    unsigned short* xT = (unsigned short*)(ws + XT_OFF);
    unsigned short* ao = (unsigned short*)(ws + AO_OFF);
    unsigned short* wqkv_bf = (unsigned short*)(ws + W_OFF);
    unsigned short* wout_bf = (unsigned short*)(ws + W_OFF + 2097152);

    hipLaunchKernelGGL(k_prep,  dim3(3072), dim3(256), 0, stream,
                       x, xT, qkvw, wqkv_bf, outw, wout_bf);
    hipLaunchKernelGGL(k_fused, dim3(512),  dim3(512), 0, stream,
                       xT, wqkv_bf, qkvb, rel, ao);
    hipLaunchKernelGGL(k_out,   dim3(512),  dim3(256), 0, stream,
                       ao, wout_bf, outb, out);
}